// Round 18
// baseline (85.554 us; speedup 1.0000x reference)
//
#include <hip/hip_runtime.h>
#include <hip/hip_bf16.h>

// FlowLayer: N=8, C=64, H=W=16, EQN=10, GR=4, num=256, unknowns=1024 per (n,gr).
// r18: conv1 CO_T 4->8 (128 conv blocks): total DS x-read traffic halves at
// constant FMA work; per-output accumulation order unchanged -> bit-identical.
// r17: barrier-free single-wave k_cg, NIT=40 (absmax floor; margin 1.74x).
// r16: k_se fused into conv1 grid. Classic PCG + DPP reductions (r14).

#define NIT 40

__device__ __forceinline__ float lane_bcast(float v, int src){
  return __int_as_float(__builtin_amdgcn_readlane(__float_as_int(v), src));
}

// ---------------- fused 3x3 conv (+ optional SE blocks 0..7) ----------------
template<int CO_T, int CO_TOTAL, int ACT, bool FUSE_SE>
__global__ __launch_bounds__(512) void k_convw(
    const float* __restrict__ xg, const float* __restrict__ xa,
    const float* __restrict__ wg, const float* __restrict__ bg,
    const float* __restrict__ wa, const float* __restrict__ ba,
    float* __restrict__ outg, float* __restrict__ outa,
    const float* __restrict__ sw1, const float* __restrict__ sb1,
    const float* __restrict__ sw2, const float* __restrict__ sb2,
    float* __restrict__ se)
{
  const int tiles = CO_TOTAL / CO_T;
  int b = blockIdx.x;
  int t = threadIdx.x;
  __shared__ float xs[64*324];            // 82.9 KB (SE path reuses the front)
  __shared__ float part[3][CO_T][256];
  if (FUSE_SE) {
    if (b < 8) {
      int n = b;
      float* pt = xs;            // 256
      float* pooled = xs + 256;  // 64
      float* h1 = xs + 320;      // 32
      if (t < 256) {
        int c = t >> 2, q = t & 3;
        const float* xp = xg + ((n*64 + c)*256) + q*64;
        float s = 0.f;
        #pragma unroll 8
        for (int j = 0; j < 64; ++j) s += xp[j];
        pt[t] = s;
      }
      __syncthreads();
      if (t < 64) pooled[t] = (pt[t*4+0]+pt[t*4+1]+pt[t*4+2]+pt[t*4+3]) * (1.f/256.f);
      __syncthreads();
      if (t < 32) {
        float a = sb1[t];
        for (int c2 = 0; c2 < 64; ++c2) a = fmaf(sw1[t*64+c2], pooled[c2], a);
        h1[t] = a >= 0.f ? a : 0.01f*a;
      }
      __syncthreads();
      if (t < 16) {
        float a = sb2[t];
        for (int c2 = 0; c2 < 32; ++c2) a = fmaf(sw2[t*32+c2], h1[c2], a);
        se[n*16+t] = 1.f/(1.f+__expf(-a));
      }
      return;
    }
    b -= 8;
  }
  int tile = b % tiles; int rem = b / tiles;
  int br = rem & 1;     int n = rem >> 1;
  const float* xin  = br ? xa : xg;
  const float* w    = br ? wa : wg;
  const float* bias = br ? ba : bg;
  float* outp       = br ? outa : outg;
  int co_base = tile * CO_T;
  int pp = t & 127, qc = t >> 7;
  int pr2 = pp >> 4, pc = pp & 15;
  int px0 = pr2*32 + pc, px1 = px0 + 16;
  int lane = t & 63;
  int cib = qc*16;
  int cil = cib + (lane & 15);
  float wv[CO_T*9];
  #pragma unroll
  for (int co = 0; co < CO_T; ++co) {
    const float* wp = w + ((size_t)(co_base+co)*64 + cil)*9;
    #pragma unroll
    for (int k = 0; k < 9; ++k) wv[co*9+k] = wp[k];
  }
  const float* xn = xin + (size_t)n*64*256;
  for (int idx = t; idx < 64*324; idx += 512) {
    int ch = idx / 324;
    int rm = idx - ch*324;
    int rr = rm / 18, cc = rm - rr*18;
    int sr = rr - 1, sc = cc - 1;
    float v = 0.f;
    if ((unsigned)sr < 16u && (unsigned)sc < 16u)
      v = xn[ch*256 + sr*16 + sc];
    xs[idx] = v;
  }
  __syncthreads();
  float accA[CO_T], accB[CO_T];
  #pragma unroll
  for (int co = 0; co < CO_T; ++co) { accA[co] = 0.f; accB[co] = 0.f; }
  #pragma unroll
  for (int ci = 0; ci < 16; ++ci) {
    const float* xr = xs + (cib+ci)*324 + (2*pr2)*18 + pc;
    float v0 = xr[0],  v1 = xr[1],  v2 = xr[2];
    float v3 = xr[18], v4 = xr[19], v5 = xr[20];
    float v6 = xr[36], v7 = xr[37], v8 = xr[38];
    float v9 = xr[54], v10 = xr[55], v11 = xr[56];
    #pragma unroll
    for (int co = 0; co < CO_T; ++co) {
      float w0 = lane_bcast(wv[co*9+0], ci);
      float w1 = lane_bcast(wv[co*9+1], ci);
      float w2 = lane_bcast(wv[co*9+2], ci);
      float w3 = lane_bcast(wv[co*9+3], ci);
      float w4 = lane_bcast(wv[co*9+4], ci);
      float w5 = lane_bcast(wv[co*9+5], ci);
      float w6 = lane_bcast(wv[co*9+6], ci);
      float w7 = lane_bcast(wv[co*9+7], ci);
      float w8 = lane_bcast(wv[co*9+8], ci);
      float aA = accA[co];
      aA = fmaf(v0,w0,aA); aA = fmaf(v1,w1,aA); aA = fmaf(v2,w2,aA);
      aA = fmaf(v3,w3,aA); aA = fmaf(v4,w4,aA); aA = fmaf(v5,w5,aA);
      aA = fmaf(v6,w6,aA); aA = fmaf(v7,w7,aA); aA = fmaf(v8,w8,aA);
      accA[co] = aA;
      float aB = accB[co];
      aB = fmaf(v3,w0,aB); aB = fmaf(v4,w1,aB); aB = fmaf(v5,w2,aB);
      aB = fmaf(v6,w3,aB); aB = fmaf(v7,w4,aB); aB = fmaf(v8,w5,aB);
      aB = fmaf(v9,w6,aB); aB = fmaf(v10,w7,aB); aB = fmaf(v11,w8,aB);
      accB[co] = aB;
    }
  }
  if (qc > 0) {
    #pragma unroll
    for (int co = 0; co < CO_T; ++co) {
      part[qc-1][co][px0] = accA[co];
      part[qc-1][co][px1] = accB[co];
    }
  }
  __syncthreads();
  if (qc == 0) {
    float* ob = outp + ((size_t)n*CO_TOTAL + co_base)*256;
    #pragma unroll
    for (int co = 0; co < CO_T; ++co) {
      float bsv = bias[co_base+co];
      float vA = bsv + accA[co] + part[0][co][px0] + part[1][co][px0] + part[2][co][px0];
      float vB = bsv + accB[co] + part[0][co][px1] + part[1][co][px1] + part[2][co][px1];
      if (ACT == 1) { vA = vA >= 0.f ? vA : 0.01f*vA; vB = vB >= 0.f ? vB : 0.01f*vB; }
      if (ACT == 2 && br) { vA = 1.f/(1.f+__expf(-vA)); vB = 1.f/(1.f+__expf(-vB)); }
      ob[co*256 + px0] = vA;
      ob[co*256 + px1] = vB;
    }
  }
}

// ---------------- DPP helpers (VALU pipe) ----------------
__device__ __forceinline__ float wave_sum(float x){
  x += __int_as_float(__builtin_amdgcn_update_dpp(0, __float_as_int(x), 0x111, 0xf, 0xf, true)); // row_shr:1
  x += __int_as_float(__builtin_amdgcn_update_dpp(0, __float_as_int(x), 0x112, 0xf, 0xf, true)); // row_shr:2
  x += __int_as_float(__builtin_amdgcn_update_dpp(0, __float_as_int(x), 0x114, 0xf, 0xf, true)); // row_shr:4
  x += __int_as_float(__builtin_amdgcn_update_dpp(0, __float_as_int(x), 0x118, 0xf, 0xf, true)); // row_shr:8
  x += __int_as_float(__builtin_amdgcn_update_dpp(0, __float_as_int(x), 0x142, 0xa, 0xf, true)); // row_bcast:15 rows{1,3}
  x += __int_as_float(__builtin_amdgcn_update_dpp(0, __float_as_int(x), 0x143, 0xc, 0xf, true)); // row_bcast:31 rows{2,3}
  return __int_as_float(__builtin_amdgcn_readlane(__float_as_int(x), 63));
}
__device__ __forceinline__ float dpp_prev(float v){  // lane i <- lane i-1; lane0 -> 0
  return __int_as_float(__builtin_amdgcn_update_dpp(0, __float_as_int(v), 0x138, 0xf, 0xf, true));
}
__device__ __forceinline__ float dpp_next(float v){  // lane i <- lane i+1; lane63 -> 0
  return __int_as_float(__builtin_amdgcn_update_dpp(0, __float_as_int(v), 0x130, 0xf, 0xf, true));
}

// ---------------- PCG solver: ONE WAVE per (n,gr) system, barrier-free --------
__global__ __launch_bounds__(64, 1) void k_cg(
    const float* __restrict__ att, const float* __restrict__ gm,
    float* __restrict__ yout)
{
  int bg = blockIdx.x;
  int n = bg >> 2, g = bg & 3;
  const float* ab = att + ((size_t)n*40 + g*10)*256;
  const float* gb = gm  + ((size_t)n*40 + g*10)*256;
  __shared__ float sbuf[10][256];
  __shared__ float tbuf[10][256];
  __shared__ float pl[4][256];
  int l = threadIdx.x;
  int base = l*4;
  int rI = l >> 2;
  int c0 = (l & 3)*4;
  bool rU4 = (rI > 0), hD4 = (rI < 15);
  int iL0 = (base > 0) ? base-1 : 0;        // setup only
  int iUc = rU4 ? base-16 : base;           // row stride 16
  int iDc = hD4 ? base+16 : base;

  float sr[10][4], tr[10][4];
  #pragma unroll
  for (int e = 0; e < 10; ++e) {
    float4 av = *(const float4*)(ab + e*256 + base);
    float4 gv = *(const float4*)(gb + e*256 + base);
    sr[e][0]=av.x*av.x; sr[e][1]=av.y*av.y; sr[e][2]=av.z*av.z; sr[e][3]=av.w*av.w;
    tr[e][0]=sr[e][0]*gv.x; tr[e][1]=sr[e][1]*gv.y; tr[e][2]=sr[e][2]*gv.z; tr[e][3]=sr[e][3]*gv.w;
    *(float4*)(&sbuf[e][base]) = make_float4(sr[e][0],sr[e][1],sr[e][2],sr[e][3]);
    *(float4*)(&tbuf[e][base]) = make_float4(tr[e][0],tr[e][1],tr[e][2],tr[e][3]);
  }

  const int eL[5] = {0,2,4,6,8};
  const int eU[5] = {1,3,5,7,9};
  float sLs[5][4], tLs[5][4], sUs[5][4], tUs[5][4];
  float gU = rU4 ? 1.f : 0.f;
  #pragma unroll
  for (int k = 0; k < 5; ++k) {
    int e = eL[k];
    sLs[k][0] = (c0 > 0) ? sbuf[e][iL0] : 0.f;
    tLs[k][0] = (c0 > 0) ? tbuf[e][iL0] : 0.f;
    #pragma unroll
    for (int j = 1; j < 4; ++j) { sLs[k][j] = sr[e][j-1]; tLs[k][j] = tr[e][j-1]; }
  }
  #pragma unroll
  for (int k = 0; k < 5; ++k) {
    int e = eU[k];
    float4 su = *(const float4*)(&sbuf[e][iUc]);
    float4 tu = *(const float4*)(&tbuf[e][iUc]);
    sUs[k][0]=su.x*gU; sUs[k][1]=su.y*gU; sUs[k][2]=su.z*gU; sUs[k][3]=su.w*gU;
    tUs[k][0]=tu.x*gU; tUs[k][1]=tu.y*gU; tUs[k][2]=tu.z*gU; tUs[k][3]=tu.w*gU;
  }

  float k0R[4],k0L[4],k0X[4],k0D[4],k0U[4], d0[4],di0[4], b0[4];
  float k1R[4],k1L[4],k1D[4],k1U[4],k1X[4], d1[4],di1[4], b1[4];
  float k2R[4],k2L[4],k2D[4],k2U[4],k2X[4], d2[4],di2[4], b2[4];
  float k3R[4],k3L[4],k3D[4],k3U[4],k3X[4], d3[4],di3[4], b3[4];
  #pragma unroll
  for (int j = 0; j < 4; ++j) {
    bool hR = (c0 + j) < 15;
    bool hD = hD4;
    bool last = (l == 63) && (j == 3);
    k0R[j] = hR ? sr[4][j] : 0.f;  k0L[j] = sLs[2][j];  k0X[j] = sLs[0][j];
    k0D[j] = hD ? sr[9][j] : 0.f;  k0U[j] = sUs[4][j];
    k1R[j] = hR ? sr[8][j] : 0.f;  k1L[j] = sLs[4][j];
    k1D[j] = hD ? sr[5][j] : 0.f;  k1U[j] = sUs[2][j];  k1X[j] = sUs[0][j];
    k2R[j] = hR ? sr[2][j] : 0.f;  k2L[j] = sLs[1][j];
    k2D[j] = hD ? sr[7][j] : 0.f;  k2U[j] = sUs[3][j];  k2X[j] = hR ? sr[0][j] : 0.f;
    k3R[j] = hR ? sr[6][j] : 0.f;  k3L[j] = sLs[3][j];
    k3D[j] = hD ? sr[3][j] : 0.f;  k3U[j] = sUs[1][j];  k3X[j] = hD ? sr[1][j] : 0.f;
    d0[j] = k0R[j]+k0L[j]+k0X[j]+k0D[j]+k0U[j] + (last ? sr[4][j]+sr[9][j] : 0.f);
    d1[j] = k1R[j]+k1L[j]+k1D[j]+k1U[j]+k1X[j] + (last ? sr[5][j]+sr[8][j] : 0.f);
    d2[j] = k2R[j]+k2L[j]+k2D[j]+k2U[j]+k2X[j] + (last ? sr[0][j]+sr[2][j]+sr[7][j] : 0.f);
    d3[j] = k3R[j]+k3L[j]+k3D[j]+k3U[j]+k3X[j] + (last ? sr[1][j]+sr[3][j]+sr[6][j] : 0.f);
    b0[j] = (hR?tr[4][j]:0.f) - tLs[2][j] - tLs[0][j] + (hD?tr[9][j]:0.f) - tUs[4][j]
          + (last ? tr[4][j]+tr[9][j] : 0.f);
    b1[j] = (hR?tr[8][j]:0.f) - tLs[4][j] + (hD?tr[5][j]:0.f) - tUs[2][j] - tUs[0][j]
          + (last ? tr[5][j]+tr[8][j] : 0.f);
    b2[j] = (hR?(tr[2][j]+tr[0][j]):0.f) - tLs[1][j] + (hD?tr[7][j]:0.f) - tUs[3][j]
          + (last ? tr[0][j]+tr[2][j]+tr[7][j] : 0.f);
    b3[j] = (hR?tr[6][j]:0.f) - tLs[3][j] + (hD?(tr[3][j]+tr[1][j]):0.f) - tUs[1][j]
          + (last ? tr[1][j]+tr[3][j]+tr[6][j] : 0.f);
    di0[j] = 1.f/(d0[j]+1e-20f); di1[j] = 1.f/(d1[j]+1e-20f);
    di2[j] = 1.f/(d2[j]+1e-20f); di3[j] = 1.f/(d3[j]+1e-20f);
  }

  float vA = sr[0][3]+sr[2][3]+sr[4][3]+sr[7][3]+sr[9][3];
  float vB = sr[1][3]+sr[3][3]+sr[5][3]+sr[6][3]+sr[8][3];
  float ei1 = 1.f/(__shfl(vA, 63, 64)+1e-20f);
  float ei2 = 1.f/(__shfl(vB, 63, 64)+1e-20f);

  float x0[4],x1[4],x2[4],x3[4], r0[4],r1[4],r2[4],r3[4], p0[4],p1[4],p2[4],p3[4];
  float rdr_p = 0.f, ca_p = 0.f, cb_p = 0.f;
  #pragma unroll
  for (int j = 0; j < 4; ++j) {
    x0[j]=0.f; x1[j]=0.f; x2[j]=0.f; x3[j]=0.f;
    r0[j]=b0[j]; r1[j]=b1[j]; r2[j]=b2[j]; r3[j]=b3[j];
    rdr_p += r0[j]*r0[j]*di0[j] + r1[j]*r1[j]*di1[j] + r2[j]*r2[j]*di2[j] + r3[j]*r3[j]*di3[j];
    ca_p += r0[j]+r2[j]; cb_p += r1[j]+r3[j];
  }
  float rdr = wave_sum(rdr_p), ca = wave_sum(ca_p), cb = wave_sum(cb_p);
  float rz = rdr + ca*ca*ei1 + cb*cb*ei2;
  float cc1 = ca*ei1, cc2 = cb*ei2;
  #pragma unroll
  for (int j = 0; j < 4; ++j) {
    p0[j] = di0[j]*r0[j] + cc1; p1[j] = di1[j]*r1[j] + cc2;
    p2[j] = di2[j]*r2[j] + cc1; p3[j] = di3[j]*r3[j] + cc2;
  }
  *(float4*)(&pl[0][base]) = make_float4(p0[0],p0[1],p0[2],p0[3]);
  *(float4*)(&pl[1][base]) = make_float4(p1[0],p1[1],p1[2],p1[3]);
  *(float4*)(&pl[2][base]) = make_float4(p2[0],p2[1],p2[2],p2[3]);
  *(float4*)(&pl[3][base]) = make_float4(p3[0],p3[1],p3[2],p3[3]);

  for (int it = 0; it < NIT; ++it) {
    float nR0 = dpp_next(p0[0]), nR1 = dpp_next(p1[0]),
          nR2 = dpp_next(p2[0]), nR3 = dpp_next(p3[0]);
    float nL0 = dpp_prev(p0[3]), nL1 = dpp_prev(p1[3]),
          nL2 = dpp_prev(p2[3]), nL3 = dpp_prev(p3[3]);
    float4 u0 = *(const float4*)(&pl[0][iUc]);
    float4 u1 = *(const float4*)(&pl[1][iUc]);
    float4 u2 = *(const float4*)(&pl[2][iUc]);
    float4 u3 = *(const float4*)(&pl[3][iUc]);
    float4 w0 = *(const float4*)(&pl[0][iDc]);
    float4 w1 = *(const float4*)(&pl[1][iDc]);
    float4 w2 = *(const float4*)(&pl[2][iDc]);
    float4 w3 = *(const float4*)(&pl[3][iDc]);
    float pU0[4]={u0.x,u0.y,u0.z,u0.w}, pU1[4]={u1.x,u1.y,u1.z,u1.w};
    float pU2[4]={u2.x,u2.y,u2.z,u2.w}, pU3[4]={u3.x,u3.y,u3.z,u3.w};
    float pD0[4]={w0.x,w0.y,w0.z,w0.w}, pD1[4]={w1.x,w1.y,w1.z,w1.w};
    float pD2[4]={w2.x,w2.y,w2.z,w2.w}, pD3[4]={w3.x,w3.y,w3.z,w3.w};
    float q0[4],q1[4],q2[4],q3[4];
    float pq_p = 0.f;
    #pragma unroll
    for (int j = 0; j < 4; ++j) {
      float p0R = (j<3)? p0[j+1] : nR0;  float p0L = (j>0)? p0[j-1] : nL0;
      float p1R = (j<3)? p1[j+1] : nR1;  float p1L = (j>0)? p1[j-1] : nL1;
      float p2R = (j<3)? p2[j+1] : nR2;  float p2L = (j>0)? p2[j-1] : nL2;
      float p3R = (j<3)? p3[j+1] : nR3;  float p3L = (j>0)? p3[j-1] : nL3;
      q0[j] = d0[j]*p0[j] - k0R[j]*p0R - k0L[j]*p0L - k0X[j]*p2L - k0D[j]*pD0[j] - k0U[j]*pU0[j];
      q1[j] = d1[j]*p1[j] - k1R[j]*p1R - k1L[j]*p1L - k1D[j]*pD1[j] - k1U[j]*pU1[j] - k1X[j]*pU3[j];
      q2[j] = d2[j]*p2[j] - k2R[j]*p2R - k2L[j]*p2L - k2D[j]*pD2[j] - k2U[j]*pU2[j] - k2X[j]*p0R;
      q3[j] = d3[j]*p3[j] - k3R[j]*p3R - k3L[j]*p3L - k3D[j]*pD3[j] - k3U[j]*pU3[j] - k3X[j]*pD1[j];
      pq_p += p0[j]*q0[j] + p1[j]*q1[j] + p2[j]*q2[j] + p3[j]*q3[j];
    }
    float pq = wave_sum(pq_p);
    float alpha = pq > 1e-35f ? rz/pq : 0.f;
    float rdr2_p = 0.f, ca2_p = 0.f, cb2_p = 0.f;
    #pragma unroll
    for (int j = 0; j < 4; ++j) {
      x0[j] = fmaf(alpha,p0[j],x0[j]); x1[j] = fmaf(alpha,p1[j],x1[j]);
      x2[j] = fmaf(alpha,p2[j],x2[j]); x3[j] = fmaf(alpha,p3[j],x3[j]);
      r0[j] = fmaf(-alpha,q0[j],r0[j]); r1[j] = fmaf(-alpha,q1[j],r1[j]);
      r2[j] = fmaf(-alpha,q2[j],r2[j]); r3[j] = fmaf(-alpha,q3[j],r3[j]);
      rdr2_p += r0[j]*r0[j]*di0[j] + r1[j]*r1[j]*di1[j] + r2[j]*r2[j]*di2[j] + r3[j]*r3[j]*di3[j];
      ca2_p += r0[j]+r2[j]; cb2_p += r1[j]+r3[j];
    }
    float rdrT = wave_sum(rdr2_p), c1T = wave_sum(ca2_p), c2T = wave_sum(cb2_p);
    float rz2 = rdrT + c1T*c1T*ei1 + c2T*c2T*ei2;
    float beta = rz > 1e-35f ? rz2/rz : 0.f;
    rz = rz2;
    float z1c = c1T*ei1, z2c = c2T*ei2;
    #pragma unroll
    for (int j = 0; j < 4; ++j) {
      p0[j] = fmaf(beta,p0[j], di0[j]*r0[j] + z1c);
      p1[j] = fmaf(beta,p1[j], di1[j]*r1[j] + z2c);
      p2[j] = fmaf(beta,p2[j], di2[j]*r2[j] + z1c);
      p3[j] = fmaf(beta,p3[j], di3[j]*r3[j] + z2c);
    }
    *(float4*)(&pl[0][base]) = make_float4(p0[0],p0[1],p0[2],p0[3]);
    *(float4*)(&pl[1][base]) = make_float4(p1[0],p1[1],p1[2],p1[3]);
    *(float4*)(&pl[2][base]) = make_float4(p2[0],p2[1],p2[2],p2[3]);
    *(float4*)(&pl[3][base]) = make_float4(p3[0],p3[1],p3[2],p3[3]);
  }
  float* yo = yout + ((size_t)n*16 + g*4)*256 + base;
  *(float4*)(yo)       = make_float4(x0[0],x0[1],x0[2],x0[3]);
  *(float4*)(yo + 256) = make_float4(x1[0],x1[1],x1[2],x1[3]);
  *(float4*)(yo + 512) = make_float4(x2[0],x2[1],x2[2],x2[3]);
  *(float4*)(yo + 768) = make_float4(x3[0],x3[1],x3[2],x3[3]);
}

// ---------------- GroupNorm + SE + final 3x3 conv 16->128, f32 out ----------------
template<int CO_T>
__global__ __launch_bounds__(256) void k_out(
    const float* __restrict__ y, const float* __restrict__ insw,
    const float* __restrict__ insb, const float* __restrict__ sev,
    const float* __restrict__ pw, const float* __restrict__ pb,
    float* __restrict__ out)
{
  const int tiles = 128 / CO_T;
  int b = blockIdx.x;
  int cot = b % tiles, n = b / tiles;
  int co_base = cot * CO_T;
  int t = threadIdx.x;
  int pr = t >> 4, pc = t & 15;
  __shared__ float ys[16*324];
  __shared__ float wl[CO_T*16*12];
  __shared__ float redA[4], redB[4];
  const float* yb = y + (size_t)n*16*256;
  float s = 0.f, s2 = 0.f;
  #pragma unroll
  for (int c = 0; c < 16; ++c) {
    float v = yb[c*256 + t];
    s += v; s2 = fmaf(v, v, s2);
  }
  for (int idx = t; idx < CO_T*144; idx += 256) {
    int co = idx / 144; int rm = idx - co*144;
    int ci = rm / 9; int k = rm - ci*9;
    wl[(co*16 + ci)*12 + k] = pw[(size_t)(co_base+co)*144 + rm];
  }
  for (int idx = t; idx < 16*324; idx += 256) {
    int ch = idx / 324;
    int rem = idx - ch*324;
    int rr = rem / 18, cc = rem - rr*18;
    int sr = rr-1, sc = cc-1;
    float v = 0.f;
    if ((unsigned)sr < 16u && (unsigned)sc < 16u) v = yb[ch*256 + sr*16 + sc];
    ys[idx] = v;
  }
  int lane = t & 63, wid = t >> 6;
  #pragma unroll
  for (int m = 1; m < 64; m <<= 1) { s += __shfl_xor(s, m, 64); s2 += __shfl_xor(s2, m, 64); }
  if (lane == 0) { redA[wid] = s; redB[wid] = s2; }
  __syncthreads();
  float S  = redA[0]+redA[1]+redA[2]+redA[3];
  float SS = redB[0]+redB[1]+redB[2]+redB[3];
  float mu = S * (1.f/4096.f);
  float var = SS * (1.f/4096.f) - mu*mu;
  float rstd = rsqrtf(var + 1e-5f);
  for (int idx = t; idx < 16*324; idx += 256) {
    int ch = idx / 324;
    int rem = idx - ch*324;
    int rr = rem / 18, cc = rem - rr*18;
    int sr = rr-1, sc = cc-1;
    if ((unsigned)sr < 16u && (unsigned)sc < 16u) {
      float sef = sev[n*16+ch];
      float m = rstd * insw[ch] * sef;
      float a = (insb[ch] - mu*rstd*insw[ch]) * sef;
      ys[idx] = fmaf(ys[idx], m, a);
    }
  }
  __syncthreads();
  float acc[CO_T];
  #pragma unroll
  for (int co = 0; co < CO_T; ++co) acc[co] = pb[co_base+co];
  for (int ci = 0; ci < 16; ++ci) {
    const float* xr = ys + ci*324 + pr*18 + pc;
    float x0 = xr[0],  x1 = xr[1],  x2 = xr[2];
    float x3 = xr[18], x4 = xr[19], x5 = xr[20];
    float x6 = xr[36], x7 = xr[37], x8 = xr[38];
    #pragma unroll
    for (int co = 0; co < CO_T; ++co) {
      const float4* wv = ((const float4*)wl) + (co*16 + ci)*3;
      float4 wa = wv[0], wb = wv[1], wc = wv[2];
      float a = acc[co];
      a = fmaf(x0,wa.x,a); a = fmaf(x1,wa.y,a); a = fmaf(x2,wa.z,a);
      a = fmaf(x3,wa.w,a); a = fmaf(x4,wb.x,a); a = fmaf(x5,wb.y,a);
      a = fmaf(x6,wb.z,a); a = fmaf(x7,wb.w,a); a = fmaf(x8,wc.x,a);
      acc[co] = a;
    }
  }
  float* ob = out + ((size_t)n*128 + co_base)*256 + t;
  #pragma unroll
  for (int co = 0; co < CO_T; ++co)
    ob[co*256] = acc[co];
}

extern "C" void kernel_launch(void* const* d_in, const int* in_sizes, int n_in,
                              void* d_out, int out_size, void* d_ws, size_t ws_size,
                              hipStream_t stream) {
  const float* x    = (const float*)d_in[0];
  // d_in[1] = 'a' (structure hardcoded analytically)
  const float* gw1  = (const float*)d_in[2];
  const float* gb1  = (const float*)d_in[3];
  const float* gw2  = (const float*)d_in[4];
  const float* gb2  = (const float*)d_in[5];
  const float* aw1  = (const float*)d_in[6];
  const float* ab1  = (const float*)d_in[7];
  const float* aw2  = (const float*)d_in[8];
  const float* ab2  = (const float*)d_in[9];
  const float* sw1  = (const float*)d_in[10];
  const float* sb1  = (const float*)d_in[11];
  const float* sw2  = (const float*)d_in[12];
  const float* sb2  = (const float*)d_in[13];
  const float* insw = (const float*)d_in[14];
  const float* insb = (const float*)d_in[15];
  const float* pw   = (const float*)d_in[16];
  const float* pb   = (const float*)d_in[17];
  float* ws = (float*)d_ws;
  float* g1   = ws;             // [8][64][256]
  float* a1   = ws + 131072;    // [8][64][256]
  float* gmat = ws + 262144;    // [8][40][256]
  float* attb = ws + 344064;    // [8][40][256]
  float* sev  = ws + 425984;    // [8][16]
  float* ybuf = ws + 426112;    // [8][16][256]
  float* out  = (float*)d_out;

  // conv1 grid: 8 SE blocks + 8 n x 2 br x 8 tiles = 136 blocks, CO_T=8
  k_convw<8,64,1,true><<<dim3(136), dim3(512), 0, stream>>>(
      x, x, gw1, gb1, aw1, ab1, g1, a1, sw1, sb1, sw2, sb2, sev);
  k_convw<4,40,2,false><<<dim3(160), dim3(512), 0, stream>>>(
      g1, a1, gw2, gb2, aw2, ab2, gmat, attb, nullptr, nullptr, nullptr, nullptr, nullptr);
  k_cg<<<dim3(32), dim3(64), 0, stream>>>(attb, gmat, ybuf);
  k_out<4><<<dim3(256), dim3(256), 0, stream>>>(ybuf, insw, insb, sev, pw, pb, out);
}

// Round 19
// 82.041 us; speedup vs baseline: 1.0428x; 1.0428x over previous
//
#include <hip/hip_runtime.h>
#include <hip/hip_bf16.h>

// FlowLayer: N=8, C=64, H=W=16, EQN=10, GR=4, num=256, unknowns=1024 per (n,gr).
// r19 = r17 verbatim (measured best: 82.3 us, absmax 0.0195).
// r18's conv1 CO_T=8 regressed (+3.2 us: longer per-wave serial chain + tail
// idle CUs outweighed halved DS traffic) -> conv CO_T=4 is the bracketed optimum.
// r17: barrier-free single-wave k_cg, NIT=40 (absmax floor; margin 1.74x).
// r16: k_se fused into conv1 grid. Classic PCG + DPP reductions (r14).

#define NIT 40

__device__ __forceinline__ float lane_bcast(float v, int src){
  return __int_as_float(__builtin_amdgcn_readlane(__float_as_int(v), src));
}

// ---------------- fused 3x3 conv (+ optional SE blocks 0..7) ----------------
template<int CO_T, int CO_TOTAL, int ACT, bool FUSE_SE>
__global__ __launch_bounds__(512) void k_convw(
    const float* __restrict__ xg, const float* __restrict__ xa,
    const float* __restrict__ wg, const float* __restrict__ bg,
    const float* __restrict__ wa, const float* __restrict__ ba,
    float* __restrict__ outg, float* __restrict__ outa,
    const float* __restrict__ sw1, const float* __restrict__ sb1,
    const float* __restrict__ sw2, const float* __restrict__ sb2,
    float* __restrict__ se)
{
  const int tiles = CO_TOTAL / CO_T;
  int b = blockIdx.x;
  int t = threadIdx.x;
  __shared__ float xs[64*324];            // 82.9 KB (SE path reuses the front)
  __shared__ float part[3][CO_T][256];    // 12 KB
  if (FUSE_SE) {
    if (b < 8) {
      int n = b;
      float* pt = xs;            // 256
      float* pooled = xs + 256;  // 64
      float* h1 = xs + 320;      // 32
      if (t < 256) {
        int c = t >> 2, q = t & 3;
        const float* xp = xg + ((n*64 + c)*256) + q*64;
        float s = 0.f;
        #pragma unroll 8
        for (int j = 0; j < 64; ++j) s += xp[j];
        pt[t] = s;
      }
      __syncthreads();
      if (t < 64) pooled[t] = (pt[t*4+0]+pt[t*4+1]+pt[t*4+2]+pt[t*4+3]) * (1.f/256.f);
      __syncthreads();
      if (t < 32) {
        float a = sb1[t];
        for (int c2 = 0; c2 < 64; ++c2) a = fmaf(sw1[t*64+c2], pooled[c2], a);
        h1[t] = a >= 0.f ? a : 0.01f*a;
      }
      __syncthreads();
      if (t < 16) {
        float a = sb2[t];
        for (int c2 = 0; c2 < 32; ++c2) a = fmaf(sw2[t*32+c2], h1[c2], a);
        se[n*16+t] = 1.f/(1.f+__expf(-a));
      }
      return;
    }
    b -= 8;
  }
  int tile = b % tiles; int rem = b / tiles;
  int br = rem & 1;     int n = rem >> 1;
  const float* xin  = br ? xa : xg;
  const float* w    = br ? wa : wg;
  const float* bias = br ? ba : bg;
  float* outp       = br ? outa : outg;
  int co_base = tile * CO_T;
  int pp = t & 127, qc = t >> 7;
  int pr2 = pp >> 4, pc = pp & 15;
  int px0 = pr2*32 + pc, px1 = px0 + 16;
  int lane = t & 63;
  int cib = qc*16;
  int cil = cib + (lane & 15);
  float wv[CO_T*9];
  #pragma unroll
  for (int co = 0; co < CO_T; ++co) {
    const float* wp = w + ((size_t)(co_base+co)*64 + cil)*9;
    #pragma unroll
    for (int k = 0; k < 9; ++k) wv[co*9+k] = wp[k];
  }
  const float* xn = xin + (size_t)n*64*256;
  for (int idx = t; idx < 64*324; idx += 512) {
    int ch = idx / 324;
    int rm = idx - ch*324;
    int rr = rm / 18, cc = rm - rr*18;
    int sr = rr - 1, sc = cc - 1;
    float v = 0.f;
    if ((unsigned)sr < 16u && (unsigned)sc < 16u)
      v = xn[ch*256 + sr*16 + sc];
    xs[idx] = v;
  }
  __syncthreads();
  float accA[CO_T], accB[CO_T];
  #pragma unroll
  for (int co = 0; co < CO_T; ++co) { accA[co] = 0.f; accB[co] = 0.f; }
  #pragma unroll
  for (int ci = 0; ci < 16; ++ci) {
    const float* xr = xs + (cib+ci)*324 + (2*pr2)*18 + pc;
    float v0 = xr[0],  v1 = xr[1],  v2 = xr[2];
    float v3 = xr[18], v4 = xr[19], v5 = xr[20];
    float v6 = xr[36], v7 = xr[37], v8 = xr[38];
    float v9 = xr[54], v10 = xr[55], v11 = xr[56];
    #pragma unroll
    for (int co = 0; co < CO_T; ++co) {
      float w0 = lane_bcast(wv[co*9+0], ci);
      float w1 = lane_bcast(wv[co*9+1], ci);
      float w2 = lane_bcast(wv[co*9+2], ci);
      float w3 = lane_bcast(wv[co*9+3], ci);
      float w4 = lane_bcast(wv[co*9+4], ci);
      float w5 = lane_bcast(wv[co*9+5], ci);
      float w6 = lane_bcast(wv[co*9+6], ci);
      float w7 = lane_bcast(wv[co*9+7], ci);
      float w8 = lane_bcast(wv[co*9+8], ci);
      float aA = accA[co];
      aA = fmaf(v0,w0,aA); aA = fmaf(v1,w1,aA); aA = fmaf(v2,w2,aA);
      aA = fmaf(v3,w3,aA); aA = fmaf(v4,w4,aA); aA = fmaf(v5,w5,aA);
      aA = fmaf(v6,w6,aA); aA = fmaf(v7,w7,aA); aA = fmaf(v8,w8,aA);
      accA[co] = aA;
      float aB = accB[co];
      aB = fmaf(v3,w0,aB); aB = fmaf(v4,w1,aB); aB = fmaf(v5,w2,aB);
      aB = fmaf(v6,w3,aB); aB = fmaf(v7,w4,aB); aB = fmaf(v8,w5,aB);
      aB = fmaf(v9,w6,aB); aB = fmaf(v10,w7,aB); aB = fmaf(v11,w8,aB);
      accB[co] = aB;
    }
  }
  if (qc > 0) {
    #pragma unroll
    for (int co = 0; co < CO_T; ++co) {
      part[qc-1][co][px0] = accA[co];
      part[qc-1][co][px1] = accB[co];
    }
  }
  __syncthreads();
  if (qc == 0) {
    float* ob = outp + ((size_t)n*CO_TOTAL + co_base)*256;
    #pragma unroll
    for (int co = 0; co < CO_T; ++co) {
      float bsv = bias[co_base+co];
      float vA = bsv + accA[co] + part[0][co][px0] + part[1][co][px0] + part[2][co][px0];
      float vB = bsv + accB[co] + part[0][co][px1] + part[1][co][px1] + part[2][co][px1];
      if (ACT == 1) { vA = vA >= 0.f ? vA : 0.01f*vA; vB = vB >= 0.f ? vB : 0.01f*vB; }
      if (ACT == 2 && br) { vA = 1.f/(1.f+__expf(-vA)); vB = 1.f/(1.f+__expf(-vB)); }
      ob[co*256 + px0] = vA;
      ob[co*256 + px1] = vB;
    }
  }
}

// ---------------- DPP helpers (VALU pipe) ----------------
__device__ __forceinline__ float wave_sum(float x){
  x += __int_as_float(__builtin_amdgcn_update_dpp(0, __float_as_int(x), 0x111, 0xf, 0xf, true)); // row_shr:1
  x += __int_as_float(__builtin_amdgcn_update_dpp(0, __float_as_int(x), 0x112, 0xf, 0xf, true)); // row_shr:2
  x += __int_as_float(__builtin_amdgcn_update_dpp(0, __float_as_int(x), 0x114, 0xf, 0xf, true)); // row_shr:4
  x += __int_as_float(__builtin_amdgcn_update_dpp(0, __float_as_int(x), 0x118, 0xf, 0xf, true)); // row_shr:8
  x += __int_as_float(__builtin_amdgcn_update_dpp(0, __float_as_int(x), 0x142, 0xa, 0xf, true)); // row_bcast:15 rows{1,3}
  x += __int_as_float(__builtin_amdgcn_update_dpp(0, __float_as_int(x), 0x143, 0xc, 0xf, true)); // row_bcast:31 rows{2,3}
  return __int_as_float(__builtin_amdgcn_readlane(__float_as_int(x), 63));
}
__device__ __forceinline__ float dpp_prev(float v){  // lane i <- lane i-1; lane0 -> 0
  return __int_as_float(__builtin_amdgcn_update_dpp(0, __float_as_int(v), 0x138, 0xf, 0xf, true));
}
__device__ __forceinline__ float dpp_next(float v){  // lane i <- lane i+1; lane63 -> 0
  return __int_as_float(__builtin_amdgcn_update_dpp(0, __float_as_int(v), 0x130, 0xf, 0xf, true));
}

// ---------------- PCG solver: ONE WAVE per (n,gr) system, barrier-free --------
// Single-wave block: DS pipe processes this wave's LDS ops in order, and all 64
// lanes issue in lockstep, so ds_write -> ds_read ordering needs no s_barrier.
__global__ __launch_bounds__(64, 1) void k_cg(
    const float* __restrict__ att, const float* __restrict__ gm,
    float* __restrict__ yout)
{
  int bg = blockIdx.x;
  int n = bg >> 2, g = bg & 3;
  const float* ab = att + ((size_t)n*40 + g*10)*256;
  const float* gb = gm  + ((size_t)n*40 + g*10)*256;
  __shared__ float sbuf[10][256];
  __shared__ float tbuf[10][256];
  __shared__ float pl[4][256];
  int l = threadIdx.x;
  int base = l*4;
  int rI = l >> 2;
  int c0 = (l & 3)*4;
  bool rU4 = (rI > 0), hD4 = (rI < 15);
  int iL0 = (base > 0) ? base-1 : 0;        // setup only
  int iUc = rU4 ? base-16 : base;           // row stride 16
  int iDc = hD4 ? base+16 : base;

  float sr[10][4], tr[10][4];
  #pragma unroll
  for (int e = 0; e < 10; ++e) {
    float4 av = *(const float4*)(ab + e*256 + base);
    float4 gv = *(const float4*)(gb + e*256 + base);
    sr[e][0]=av.x*av.x; sr[e][1]=av.y*av.y; sr[e][2]=av.z*av.z; sr[e][3]=av.w*av.w;
    tr[e][0]=sr[e][0]*gv.x; tr[e][1]=sr[e][1]*gv.y; tr[e][2]=sr[e][2]*gv.z; tr[e][3]=sr[e][3]*gv.w;
    *(float4*)(&sbuf[e][base]) = make_float4(sr[e][0],sr[e][1],sr[e][2],sr[e][3]);
    *(float4*)(&tbuf[e][base]) = make_float4(tr[e][0],tr[e][1],tr[e][2],tr[e][3]);
  }

  const int eL[5] = {0,2,4,6,8};
  const int eU[5] = {1,3,5,7,9};
  float sLs[5][4], tLs[5][4], sUs[5][4], tUs[5][4];
  float gU = rU4 ? 1.f : 0.f;
  #pragma unroll
  for (int k = 0; k < 5; ++k) {
    int e = eL[k];
    sLs[k][0] = (c0 > 0) ? sbuf[e][iL0] : 0.f;
    tLs[k][0] = (c0 > 0) ? tbuf[e][iL0] : 0.f;
    #pragma unroll
    for (int j = 1; j < 4; ++j) { sLs[k][j] = sr[e][j-1]; tLs[k][j] = tr[e][j-1]; }
  }
  #pragma unroll
  for (int k = 0; k < 5; ++k) {
    int e = eU[k];
    float4 su = *(const float4*)(&sbuf[e][iUc]);
    float4 tu = *(const float4*)(&tbuf[e][iUc]);
    sUs[k][0]=su.x*gU; sUs[k][1]=su.y*gU; sUs[k][2]=su.z*gU; sUs[k][3]=su.w*gU;
    tUs[k][0]=tu.x*gU; tUs[k][1]=tu.y*gU; tUs[k][2]=tu.z*gU; tUs[k][3]=tu.w*gU;
  }

  float k0R[4],k0L[4],k0X[4],k0D[4],k0U[4], d0[4],di0[4], b0[4];
  float k1R[4],k1L[4],k1D[4],k1U[4],k1X[4], d1[4],di1[4], b1[4];
  float k2R[4],k2L[4],k2D[4],k2U[4],k2X[4], d2[4],di2[4], b2[4];
  float k3R[4],k3L[4],k3D[4],k3U[4],k3X[4], d3[4],di3[4], b3[4];
  #pragma unroll
  for (int j = 0; j < 4; ++j) {
    bool hR = (c0 + j) < 15;
    bool hD = hD4;
    bool last = (l == 63) && (j == 3);
    k0R[j] = hR ? sr[4][j] : 0.f;  k0L[j] = sLs[2][j];  k0X[j] = sLs[0][j];
    k0D[j] = hD ? sr[9][j] : 0.f;  k0U[j] = sUs[4][j];
    k1R[j] = hR ? sr[8][j] : 0.f;  k1L[j] = sLs[4][j];
    k1D[j] = hD ? sr[5][j] : 0.f;  k1U[j] = sUs[2][j];  k1X[j] = sUs[0][j];
    k2R[j] = hR ? sr[2][j] : 0.f;  k2L[j] = sLs[1][j];
    k2D[j] = hD ? sr[7][j] : 0.f;  k2U[j] = sUs[3][j];  k2X[j] = hR ? sr[0][j] : 0.f;
    k3R[j] = hR ? sr[6][j] : 0.f;  k3L[j] = sLs[3][j];
    k3D[j] = hD ? sr[3][j] : 0.f;  k3U[j] = sUs[1][j];  k3X[j] = hD ? sr[1][j] : 0.f;
    d0[j] = k0R[j]+k0L[j]+k0X[j]+k0D[j]+k0U[j] + (last ? sr[4][j]+sr[9][j] : 0.f);
    d1[j] = k1R[j]+k1L[j]+k1D[j]+k1U[j]+k1X[j] + (last ? sr[5][j]+sr[8][j] : 0.f);
    d2[j] = k2R[j]+k2L[j]+k2D[j]+k2U[j]+k2X[j] + (last ? sr[0][j]+sr[2][j]+sr[7][j] : 0.f);
    d3[j] = k3R[j]+k3L[j]+k3D[j]+k3U[j]+k3X[j] + (last ? sr[1][j]+sr[3][j]+sr[6][j] : 0.f);
    b0[j] = (hR?tr[4][j]:0.f) - tLs[2][j] - tLs[0][j] + (hD?tr[9][j]:0.f) - tUs[4][j]
          + (last ? tr[4][j]+tr[9][j] : 0.f);
    b1[j] = (hR?tr[8][j]:0.f) - tLs[4][j] + (hD?tr[5][j]:0.f) - tUs[2][j] - tUs[0][j]
          + (last ? tr[5][j]+tr[8][j] : 0.f);
    b2[j] = (hR?(tr[2][j]+tr[0][j]):0.f) - tLs[1][j] + (hD?tr[7][j]:0.f) - tUs[3][j]
          + (last ? tr[0][j]+tr[2][j]+tr[7][j] : 0.f);
    b3[j] = (hR?tr[6][j]:0.f) - tLs[3][j] + (hD?(tr[3][j]+tr[1][j]):0.f) - tUs[1][j]
          + (last ? tr[1][j]+tr[3][j]+tr[6][j] : 0.f);
    di0[j] = 1.f/(d0[j]+1e-20f); di1[j] = 1.f/(d1[j]+1e-20f);
    di2[j] = 1.f/(d2[j]+1e-20f); di3[j] = 1.f/(d3[j]+1e-20f);
  }

  float vA = sr[0][3]+sr[2][3]+sr[4][3]+sr[7][3]+sr[9][3];
  float vB = sr[1][3]+sr[3][3]+sr[5][3]+sr[6][3]+sr[8][3];
  float ei1 = 1.f/(__shfl(vA, 63, 64)+1e-20f);
  float ei2 = 1.f/(__shfl(vB, 63, 64)+1e-20f);

  float x0[4],x1[4],x2[4],x3[4], r0[4],r1[4],r2[4],r3[4], p0[4],p1[4],p2[4],p3[4];
  float rdr_p = 0.f, ca_p = 0.f, cb_p = 0.f;
  #pragma unroll
  for (int j = 0; j < 4; ++j) {
    x0[j]=0.f; x1[j]=0.f; x2[j]=0.f; x3[j]=0.f;
    r0[j]=b0[j]; r1[j]=b1[j]; r2[j]=b2[j]; r3[j]=b3[j];
    rdr_p += r0[j]*r0[j]*di0[j] + r1[j]*r1[j]*di1[j] + r2[j]*r2[j]*di2[j] + r3[j]*r3[j]*di3[j];
    ca_p += r0[j]+r2[j]; cb_p += r1[j]+r3[j];
  }
  float rdr = wave_sum(rdr_p), ca = wave_sum(ca_p), cb = wave_sum(cb_p);
  float rz = rdr + ca*ca*ei1 + cb*cb*ei2;
  float cc1 = ca*ei1, cc2 = cb*ei2;
  #pragma unroll
  for (int j = 0; j < 4; ++j) {
    p0[j] = di0[j]*r0[j] + cc1; p1[j] = di1[j]*r1[j] + cc2;
    p2[j] = di2[j]*r2[j] + cc1; p3[j] = di3[j]*r3[j] + cc2;
  }
  *(float4*)(&pl[0][base]) = make_float4(p0[0],p0[1],p0[2],p0[3]);
  *(float4*)(&pl[1][base]) = make_float4(p1[0],p1[1],p1[2],p1[3]);
  *(float4*)(&pl[2][base]) = make_float4(p2[0],p2[1],p2[2],p2[3]);
  *(float4*)(&pl[3][base]) = make_float4(p3[0],p3[1],p3[2],p3[3]);

  for (int it = 0; it < NIT; ++it) {
    float nR0 = dpp_next(p0[0]), nR1 = dpp_next(p1[0]),
          nR2 = dpp_next(p2[0]), nR3 = dpp_next(p3[0]);
    float nL0 = dpp_prev(p0[3]), nL1 = dpp_prev(p1[3]),
          nL2 = dpp_prev(p2[3]), nL3 = dpp_prev(p3[3]);
    float4 u0 = *(const float4*)(&pl[0][iUc]);
    float4 u1 = *(const float4*)(&pl[1][iUc]);
    float4 u2 = *(const float4*)(&pl[2][iUc]);
    float4 u3 = *(const float4*)(&pl[3][iUc]);
    float4 w0 = *(const float4*)(&pl[0][iDc]);
    float4 w1 = *(const float4*)(&pl[1][iDc]);
    float4 w2 = *(const float4*)(&pl[2][iDc]);
    float4 w3 = *(const float4*)(&pl[3][iDc]);
    float pU0[4]={u0.x,u0.y,u0.z,u0.w}, pU1[4]={u1.x,u1.y,u1.z,u1.w};
    float pU2[4]={u2.x,u2.y,u2.z,u2.w}, pU3[4]={u3.x,u3.y,u3.z,u3.w};
    float pD0[4]={w0.x,w0.y,w0.z,w0.w}, pD1[4]={w1.x,w1.y,w1.z,w1.w};
    float pD2[4]={w2.x,w2.y,w2.z,w2.w}, pD3[4]={w3.x,w3.y,w3.z,w3.w};
    float q0[4],q1[4],q2[4],q3[4];
    float pq_p = 0.f;
    #pragma unroll
    for (int j = 0; j < 4; ++j) {
      float p0R = (j<3)? p0[j+1] : nR0;  float p0L = (j>0)? p0[j-1] : nL0;
      float p1R = (j<3)? p1[j+1] : nR1;  float p1L = (j>0)? p1[j-1] : nL1;
      float p2R = (j<3)? p2[j+1] : nR2;  float p2L = (j>0)? p2[j-1] : nL2;
      float p3R = (j<3)? p3[j+1] : nR3;  float p3L = (j>0)? p3[j-1] : nL3;
      q0[j] = d0[j]*p0[j] - k0R[j]*p0R - k0L[j]*p0L - k0X[j]*p2L - k0D[j]*pD0[j] - k0U[j]*pU0[j];
      q1[j] = d1[j]*p1[j] - k1R[j]*p1R - k1L[j]*p1L - k1D[j]*pD1[j] - k1U[j]*pU1[j] - k1X[j]*pU3[j];
      q2[j] = d2[j]*p2[j] - k2R[j]*p2R - k2L[j]*p2L - k2D[j]*pD2[j] - k2U[j]*pU2[j] - k2X[j]*p0R;
      q3[j] = d3[j]*p3[j] - k3R[j]*p3R - k3L[j]*p3L - k3D[j]*pD3[j] - k3U[j]*pU3[j] - k3X[j]*pD1[j];
      pq_p += p0[j]*q0[j] + p1[j]*q1[j] + p2[j]*q2[j] + p3[j]*q3[j];
    }
    float pq = wave_sum(pq_p);
    float alpha = pq > 1e-35f ? rz/pq : 0.f;
    float rdr2_p = 0.f, ca2_p = 0.f, cb2_p = 0.f;
    #pragma unroll
    for (int j = 0; j < 4; ++j) {
      x0[j] = fmaf(alpha,p0[j],x0[j]); x1[j] = fmaf(alpha,p1[j],x1[j]);
      x2[j] = fmaf(alpha,p2[j],x2[j]); x3[j] = fmaf(alpha,p3[j],x3[j]);
      r0[j] = fmaf(-alpha,q0[j],r0[j]); r1[j] = fmaf(-alpha,q1[j],r1[j]);
      r2[j] = fmaf(-alpha,q2[j],r2[j]); r3[j] = fmaf(-alpha,q3[j],r3[j]);
      rdr2_p += r0[j]*r0[j]*di0[j] + r1[j]*r1[j]*di1[j] + r2[j]*r2[j]*di2[j] + r3[j]*r3[j]*di3[j];
      ca2_p += r0[j]+r2[j]; cb2_p += r1[j]+r3[j];
    }
    float rdrT = wave_sum(rdr2_p), c1T = wave_sum(ca2_p), c2T = wave_sum(cb2_p);
    float rz2 = rdrT + c1T*c1T*ei1 + c2T*c2T*ei2;
    float beta = rz > 1e-35f ? rz2/rz : 0.f;
    rz = rz2;
    float z1c = c1T*ei1, z2c = c2T*ei2;
    #pragma unroll
    for (int j = 0; j < 4; ++j) {
      p0[j] = fmaf(beta,p0[j], di0[j]*r0[j] + z1c);
      p1[j] = fmaf(beta,p1[j], di1[j]*r1[j] + z2c);
      p2[j] = fmaf(beta,p2[j], di2[j]*r2[j] + z1c);
      p3[j] = fmaf(beta,p3[j], di3[j]*r3[j] + z2c);
    }
    *(float4*)(&pl[0][base]) = make_float4(p0[0],p0[1],p0[2],p0[3]);
    *(float4*)(&pl[1][base]) = make_float4(p1[0],p1[1],p1[2],p1[3]);
    *(float4*)(&pl[2][base]) = make_float4(p2[0],p2[1],p2[2],p2[3]);
    *(float4*)(&pl[3][base]) = make_float4(p3[0],p3[1],p3[2],p3[3]);
  }
  float* yo = yout + ((size_t)n*16 + g*4)*256 + base;
  *(float4*)(yo)       = make_float4(x0[0],x0[1],x0[2],x0[3]);
  *(float4*)(yo + 256) = make_float4(x1[0],x1[1],x1[2],x1[3]);
  *(float4*)(yo + 512) = make_float4(x2[0],x2[1],x2[2],x2[3]);
  *(float4*)(yo + 768) = make_float4(x3[0],x3[1],x3[2],x3[3]);
}

// ---------------- GroupNorm + SE + final 3x3 conv 16->128, f32 out ----------------
template<int CO_T>
__global__ __launch_bounds__(256) void k_out(
    const float* __restrict__ y, const float* __restrict__ insw,
    const float* __restrict__ insb, const float* __restrict__ sev,
    const float* __restrict__ pw, const float* __restrict__ pb,
    float* __restrict__ out)
{
  const int tiles = 128 / CO_T;
  int b = blockIdx.x;
  int cot = b % tiles, n = b / tiles;
  int co_base = cot * CO_T;
  int t = threadIdx.x;
  int pr = t >> 4, pc = t & 15;
  __shared__ float ys[16*324];
  __shared__ float wl[CO_T*16*12];
  __shared__ float redA[4], redB[4];
  const float* yb = y + (size_t)n*16*256;
  float s = 0.f, s2 = 0.f;
  #pragma unroll
  for (int c = 0; c < 16; ++c) {
    float v = yb[c*256 + t];
    s += v; s2 = fmaf(v, v, s2);
  }
  for (int idx = t; idx < CO_T*144; idx += 256) {
    int co = idx / 144; int rm = idx - co*144;
    int ci = rm / 9; int k = rm - ci*9;
    wl[(co*16 + ci)*12 + k] = pw[(size_t)(co_base+co)*144 + rm];
  }
  for (int idx = t; idx < 16*324; idx += 256) {
    int ch = idx / 324;
    int rem = idx - ch*324;
    int rr = rem / 18, cc = rem - rr*18;
    int sr = rr-1, sc = cc-1;
    float v = 0.f;
    if ((unsigned)sr < 16u && (unsigned)sc < 16u) v = yb[ch*256 + sr*16 + sc];
    ys[idx] = v;
  }
  int lane = t & 63, wid = t >> 6;
  #pragma unroll
  for (int m = 1; m < 64; m <<= 1) { s += __shfl_xor(s, m, 64); s2 += __shfl_xor(s2, m, 64); }
  if (lane == 0) { redA[wid] = s; redB[wid] = s2; }
  __syncthreads();
  float S  = redA[0]+redA[1]+redA[2]+redA[3];
  float SS = redB[0]+redB[1]+redB[2]+redB[3];
  float mu = S * (1.f/4096.f);
  float var = SS * (1.f/4096.f) - mu*mu;
  float rstd = rsqrtf(var + 1e-5f);
  for (int idx = t; idx < 16*324; idx += 256) {
    int ch = idx / 324;
    int rem = idx - ch*324;
    int rr = rem / 18, cc = rem - rr*18;
    int sr = rr-1, sc = cc-1;
    if ((unsigned)sr < 16u && (unsigned)sc < 16u) {
      float sef = sev[n*16+ch];
      float m = rstd * insw[ch] * sef;
      float a = (insb[ch] - mu*rstd*insw[ch]) * sef;
      ys[idx] = fmaf(ys[idx], m, a);
    }
  }
  __syncthreads();
  float acc[CO_T];
  #pragma unroll
  for (int co = 0; co < CO_T; ++co) acc[co] = pb[co_base+co];
  for (int ci = 0; ci < 16; ++ci) {
    const float* xr = ys + ci*324 + pr*18 + pc;
    float x0 = xr[0],  x1 = xr[1],  x2 = xr[2];
    float x3 = xr[18], x4 = xr[19], x5 = xr[20];
    float x6 = xr[36], x7 = xr[37], x8 = xr[38];
    #pragma unroll
    for (int co = 0; co < CO_T; ++co) {
      const float4* wv = ((const float4*)wl) + (co*16 + ci)*3;
      float4 wa = wv[0], wb = wv[1], wc = wv[2];
      float a = acc[co];
      a = fmaf(x0,wa.x,a); a = fmaf(x1,wa.y,a); a = fmaf(x2,wa.z,a);
      a = fmaf(x3,wa.w,a); a = fmaf(x4,wb.x,a); a = fmaf(x5,wb.y,a);
      a = fmaf(x6,wb.z,a); a = fmaf(x7,wb.w,a); a = fmaf(x8,wc.x,a);
      acc[co] = a;
    }
  }
  float* ob = out + ((size_t)n*128 + co_base)*256 + t;
  #pragma unroll
  for (int co = 0; co < CO_T; ++co)
    ob[co*256] = acc[co];
}

extern "C" void kernel_launch(void* const* d_in, const int* in_sizes, int n_in,
                              void* d_out, int out_size, void* d_ws, size_t ws_size,
                              hipStream_t stream) {
  const float* x    = (const float*)d_in[0];
  // d_in[1] = 'a' (structure hardcoded analytically)
  const float* gw1  = (const float*)d_in[2];
  const float* gb1  = (const float*)d_in[3];
  const float* gw2  = (const float*)d_in[4];
  const float* gb2  = (const float*)d_in[5];
  const float* aw1  = (const float*)d_in[6];
  const float* ab1  = (const float*)d_in[7];
  const float* aw2  = (const float*)d_in[8];
  const float* ab2  = (const float*)d_in[9];
  const float* sw1  = (const float*)d_in[10];
  const float* sb1  = (const float*)d_in[11];
  const float* sw2  = (const float*)d_in[12];
  const float* sb2  = (const float*)d_in[13];
  const float* insw = (const float*)d_in[14];
  const float* insb = (const float*)d_in[15];
  const float* pw   = (const float*)d_in[16];
  const float* pb   = (const float*)d_in[17];
  float* ws = (float*)d_ws;
  float* g1   = ws;             // [8][64][256]
  float* a1   = ws + 131072;    // [8][64][256]
  float* gmat = ws + 262144;    // [8][40][256]
  float* attb = ws + 344064;    // [8][40][256]
  float* sev  = ws + 425984;    // [8][16]
  float* ybuf = ws + 426112;    // [8][16][256]
  float* out  = (float*)d_out;

  k_convw<4,64,1,true><<<dim3(264), dim3(512), 0, stream>>>(
      x, x, gw1, gb1, aw1, ab1, g1, a1, sw1, sb1, sw2, sb2, sev);
  k_convw<4,40,2,false><<<dim3(160), dim3(512), 0, stream>>>(
      g1, a1, gw2, gb2, aw2, ab2, gmat, attb, nullptr, nullptr, nullptr, nullptr, nullptr);
  k_cg<<<dim3(32), dim3(64), 0, stream>>>(attb, gmat, ybuf);
  k_out<4><<<dim3(256), dim3(256), 0, stream>>>(ybuf, insw, insb, sev, pw, pb, out);
}